// Round 1
// baseline (2764.208 us; speedup 1.0000x reference)
//
#include <hip/hip_runtime.h>
#include <math.h>

#define NN 100000
#define NE 600000
#define NG 64
#define HD 128
#define NL 6

// ---------------- CSR build ----------------

__global__ __launch_bounds__(256) void k_hist(const int* __restrict__ ei, int* __restrict__ counts) {
    int e = blockIdx.x * 256 + threadIdx.x;
    if (e < NE) atomicAdd(&counts[ei[NE + e]], 1);
}

__global__ __launch_bounds__(256) void k_scan1(const int* __restrict__ counts, int* __restrict__ bsums) {
    __shared__ int s[256];
    int i = blockIdx.x * 256 + threadIdx.x;
    s[threadIdx.x] = (i < NN) ? counts[i] : 0;
    __syncthreads();
    for (int off = 128; off > 0; off >>= 1) {
        if (threadIdx.x < off) s[threadIdx.x] += s[threadIdx.x + off];
        __syncthreads();
    }
    if (threadIdx.x == 0) bsums[blockIdx.x] = s[0];
}

__global__ __launch_bounds__(512) void k_scan2(int* __restrict__ bsums, int nb) {
    __shared__ int s[512];
    int t = threadIdx.x;
    s[t] = (t < nb) ? bsums[t] : 0;
    __syncthreads();
    for (int off = 1; off < 512; off <<= 1) {
        int v = (t >= off) ? s[t - off] : 0;
        __syncthreads();
        s[t] += v;
        __syncthreads();
    }
    if (t < nb) bsums[t] = (t == 0) ? 0 : s[t - 1];
}

__global__ __launch_bounds__(256) void k_scan3(const int* __restrict__ counts, const int* __restrict__ bsums,
                                               int* __restrict__ rowptr) {
    __shared__ int s[256];
    int t = threadIdx.x;
    int i = blockIdx.x * 256 + t;
    int v = (i < NN) ? counts[i] : 0;
    s[t] = v;
    __syncthreads();
    for (int off = 1; off < 256; off <<= 1) {
        int u = (t >= off) ? s[t - off] : 0;
        __syncthreads();
        s[t] += u;
        __syncthreads();
    }
    if (i < NN) rowptr[i] = bsums[blockIdx.x] + s[t] - v;
    if (i == 0) rowptr[NN] = NE;
}

__global__ __launch_bounds__(256) void k_fill(const int* __restrict__ ei, const int* __restrict__ rowptr,
                                              int* __restrict__ cursor, int* __restrict__ colsrc) {
    int e = blockIdx.x * 256 + threadIdx.x;
    if (e < NE) {
        int d = ei[NE + e];
        int pos = rowptr[d] + atomicAdd(&cursor[d], 1);
        colsrc[pos] = ei[e];
    }
}

// ---------------- Aggregation (one wave per node) ----------------
// t[n] = scale .* (sum of f[src] over in-edges) + deg(n) * shift
// scale/shift derived on the fly from prev layer's BN stats; identity for layer 0.

__global__ __launch_bounds__(256) void k_agg(
    const float* __restrict__ f, const int* __restrict__ rowptr,
    const int* __restrict__ colsrc, const float* __restrict__ stats,
    const float* __restrict__ bng, const float* __restrict__ bnb,
    float* __restrict__ tout) {
    int n = (blockIdx.x * 256 + threadIdx.x) >> 6;
    int lane = threadIdx.x & 63;
    if (n >= NN) return;
    int beg = rowptr[n], end = rowptr[n + 1];
    const float2* f2 = (const float2*)f;
    float ax = 0.f, ay = 0.f;
    for (int e = beg; e < end; ++e) {
        int s = colsrc[e];
        float2 v = f2[(size_t)s * 64 + lane];
        ax += v.x;
        ay += v.y;
    }
    float deg = (float)(end - beg);
    float ox, oy;
    if (stats != nullptr) {
        int c0 = lane * 2;
        const float inv_n = 1.0f / (float)NN;
        float m0 = stats[c0] * inv_n, m1 = stats[c0 + 1] * inv_n;
        float var0 = fmaf(-m0, m0, stats[HD + c0] * inv_n);
        float var1 = fmaf(-m1, m1, stats[HD + c0 + 1] * inv_n);
        float sc0 = bng[c0] * rsqrtf(var0 + 1e-5f);
        float sc1 = bng[c0 + 1] * rsqrtf(var1 + 1e-5f);
        float sh0 = bnb[c0] - m0 * sc0;
        float sh1 = bnb[c0 + 1] - m1 * sc1;
        ox = fmaf(sc0, ax, deg * sh0);
        oy = fmaf(sc1, ay, deg * sh1);
    } else {
        ox = ax;
        oy = ay;
    }
    float2 o;
    o.x = ox;
    o.y = oy;
    ((float2*)tout)[(size_t)n * 64 + lane] = o;
}

// ---------------- Conv GEMM: H = relu(T @ W + b), accumulate BN stats ----------------
// 64-row tile per block; A transposed in LDS (stride 68, conflict-light);
// W streamed from global (L1/L2-resident, broadcast reads). Thread tile 4 rows x 8 cols.
// In-place safe (T == Hout): block stages its own 64 rows before any store.

__global__ __launch_bounds__(256) void k_conv(
    const float* T, const float* __restrict__ W,
    const float* __restrict__ bias, float* Hout,
    float* __restrict__ stats) {
    __shared__ float At[128 * 68];
    int t = threadIdx.x;
    int row0 = blockIdx.x * 64;
    // stage 64 rows x 128 cols, transposed. 4-way-bank-conflict writes by construction.
    #pragma unroll
    for (int it = 0; it < 8; ++it) {
        int u = t + 256 * it;
        int l = u & 63;
        int gn = u >> 6;
        int r = 8 * (gn & 7) + (l >> 3);
        int k4 = 8 * (gn >> 3) + (l & 7);
        float4 v = make_float4(0.f, 0.f, 0.f, 0.f);
        int row = row0 + r;
        if (row < NN) v = ((const float4*)T)[(size_t)row * 32 + k4];
        int k = 4 * k4;
        At[(k + 0) * 68 + r] = v.x;
        At[(k + 1) * 68 + r] = v.y;
        At[(k + 2) * 68 + r] = v.z;
        At[(k + 3) * 68 + r] = v.w;
    }
    __syncthreads();
    int rg = t & 15, cg = t >> 4;
    int r0 = 4 * rg, c0 = 8 * cg;
    float acc[4][8];
    #pragma unroll
    for (int i = 0; i < 4; ++i)
        #pragma unroll
        for (int j = 0; j < 8; ++j) acc[i][j] = 0.f;
    #pragma unroll 4
    for (int k = 0; k < 128; ++k) {
        float4 a = *(const float4*)&At[k * 68 + r0];
        const float4* wp = (const float4*)&W[k * 128 + c0];
        float4 w0 = wp[0];
        float4 w1 = wp[1];
        float av[4] = {a.x, a.y, a.z, a.w};
        float wv[8] = {w0.x, w0.y, w0.z, w0.w, w1.x, w1.y, w1.z, w1.w};
        #pragma unroll
        for (int i = 0; i < 4; ++i)
            #pragma unroll
            for (int j = 0; j < 8; ++j) acc[i][j] = fmaf(av[i], wv[j], acc[i][j]);
    }
    float bsv[8];
    #pragma unroll
    for (int j = 0; j < 8; ++j) bsv[j] = bias[c0 + j];
    float lsum[8], lsq[8];
    #pragma unroll
    for (int j = 0; j < 8; ++j) { lsum[j] = 0.f; lsq[j] = 0.f; }
    #pragma unroll
    for (int i = 0; i < 4; ++i) {
        int row = row0 + r0 + i;
        if (row < NN) {
            float vals[8];
            #pragma unroll
            for (int j = 0; j < 8; ++j) {
                float v = fmaxf(acc[i][j] + bsv[j], 0.f);
                vals[j] = v;
                lsum[j] += v;
                lsq[j] = fmaf(v, v, lsq[j]);
            }
            float4* dst = (float4*)&Hout[(size_t)row * 128 + c0];
            dst[0] = make_float4(vals[0], vals[1], vals[2], vals[3]);
            dst[1] = make_float4(vals[4], vals[5], vals[6], vals[7]);
        }
    }
    // reduce across the 16 rg-lanes (lane bits 0..3), then one atomic row per block
    #pragma unroll
    for (int off = 1; off < 16; off <<= 1) {
        #pragma unroll
        for (int j = 0; j < 8; ++j) {
            lsum[j] += __shfl_xor(lsum[j], off, 64);
            lsq[j] += __shfl_xor(lsq[j], off, 64);
        }
    }
    if (rg == 0) {
        #pragma unroll
        for (int j = 0; j < 8; ++j) {
            atomicAdd(&stats[c0 + j], lsum[j]);
            atomicAdd(&stats[HD + c0 + j], lsq[j]);
        }
    }
}

// ---------------- Pooling (one block per graph; batch is sorted) ----------------

__device__ __forceinline__ int lowerb(const int* __restrict__ b, int n, int key) {
    int lo = 0, hi = n;
    while (lo < hi) {
        int mid = (lo + hi) >> 1;
        if (b[mid] < key) lo = mid + 1;
        else hi = mid;
    }
    return lo;
}

__global__ __launch_bounds__(256) void k_pool(
    const float* __restrict__ h, const int* __restrict__ batch,
    const float* __restrict__ stats, const float* __restrict__ bng, const float* __restrict__ bnb,
    float* __restrict__ pooled) {
    int g = blockIdx.x;
    int lo = lowerb(batch, NN, g);
    int hi = lowerb(batch, NN, g + 1);
    int wave = threadIdx.x >> 6, lane = threadIdx.x & 63;
    const float2* h2 = (const float2*)h;
    float ax = 0.f, ay = 0.f;
    for (int n = lo + wave; n < hi; n += 4) {
        float2 v = h2[(size_t)n * 64 + lane];
        ax += v.x;
        ay += v.y;
    }
    __shared__ float2 red[4][64];
    red[wave][lane] = make_float2(ax, ay);
    __syncthreads();
    if (wave == 0) {
        float sx = 0.f, sy = 0.f;
        for (int w = 0; w < 4; ++w) {
            sx += red[w][lane].x;
            sy += red[w][lane].y;
        }
        int cnt = hi - lo;
        int c0 = lane * 2;
        const float inv_n = 1.0f / (float)NN;
        float m0 = stats[c0] * inv_n, m1 = stats[c0 + 1] * inv_n;
        float var0 = fmaf(-m0, m0, stats[HD + c0] * inv_n);
        float var1 = fmaf(-m1, m1, stats[HD + c0 + 1] * inv_n);
        float sc0 = bng[c0] * rsqrtf(var0 + 1e-5f);
        float sc1 = bng[c0 + 1] * rsqrtf(var1 + 1e-5f);
        float sh0 = bnb[c0] - m0 * sc0;
        float sh1 = bnb[c0 + 1] - m1 * sc1;
        float denom = fmaxf((float)cnt, 1.f);
        float2 o;
        o.x = (sc0 * sx + (float)cnt * sh0) / denom;
        o.y = (sc1 * sy + (float)cnt * sh1) / denom;
        ((float2*)pooled)[g * 64 + lane] = o;
    }
}

// ---------------- MLP head + log_softmax (one wave per graph) ----------------

__global__ __launch_bounds__(64) void k_head(
    const float* __restrict__ pooled, const float* __restrict__ w1, const float* __restrict__ b1,
    const float* __restrict__ w2, const float* __restrict__ b2, float* __restrict__ out) {
    int g = blockIdx.x;
    int j = threadIdx.x;  // 0..63
    float hid = b1[j];
    const float* p = pooled + g * 128;
    #pragma unroll 8
    for (int k = 0; k < 128; ++k) hid = fmaf(p[k], w1[k * 64 + j], hid);
    float o[4];
    #pragma unroll
    for (int c = 0; c < 4; ++c) {
        float v = hid * w2[j * 4 + c];
        #pragma unroll
        for (int off = 1; off < 64; off <<= 1) v += __shfl_xor(v, off, 64);
        o[c] = v + b2[c];
    }
    if (j == 0) {
        float mx = fmaxf(fmaxf(o[0], o[1]), fmaxf(o[2], o[3]));
        float se = expf(o[0] - mx) + expf(o[1] - mx) + expf(o[2] - mx) + expf(o[3] - mx);
        float ls = mx + logf(se);
        #pragma unroll
        for (int c = 0; c < 4; ++c) out[g * 4 + c] = o[c] - ls;
    }
}

extern "C" void kernel_launch(void* const* d_in, const int* in_sizes, int n_in,
                              void* d_out, int out_size, void* d_ws, size_t ws_size,
                              hipStream_t stream) {
    const float* x = (const float*)d_in[0];
    const int* ei = (const int*)d_in[1];
    const int* batch = (const int*)d_in[2];
    const float* conv_w = (const float*)d_in[3];
    const float* conv_b = (const float*)d_in[4];
    const float* bn_g = (const float*)d_in[5];
    const float* bn_b = (const float*)d_in[6];
    const float* l1w = (const float*)d_in[7];
    const float* l1b = (const float*)d_in[8];
    const float* l2w = (const float*)d_in[9];
    const float* l2b = (const float*)d_in[10];
    float* out = (float*)d_out;
    (void)in_sizes; (void)n_in; (void)out_size; (void)ws_size;

    char* ws = (char*)d_ws;
    int* counts = (int*)(ws + 0);             // 400000 B
    int* cursor = (int*)(ws + 400000);        // 400000 B
    float* stats = (float*)(ws + 800000);     // 6*256 floats = 6144 B
    const size_t zero_bytes = 806144;         // counts + cursor + stats
    int* rowptr = (int*)(ws + 806144);        // 100001 ints
    int* bsums = (int*)(ws + 1206400);        // 391 ints
    int* colsrc = (int*)(ws + 1208192);       // 600000 ints
    float* pooled = (float*)(ws + 3608192);   // 64*128 floats
    float* bufA = (float*)(ws + 3641344);     // 51200000 B (512-aligned)
    float* bufB = (float*)(ws + 54841344);    // 51200000 B (512-aligned)

    hipMemsetAsync(ws, 0, zero_bytes, stream);

    int ebl = (NE + 255) / 256;
    int nb1 = (NN + 255) / 256;  // 391
    k_hist<<<ebl, 256, 0, stream>>>(ei, counts);
    k_scan1<<<nb1, 256, 0, stream>>>(counts, bsums);
    k_scan2<<<1, 512, 0, stream>>>(bsums, nb1);
    k_scan3<<<nb1, 256, 0, stream>>>(counts, bsums, rowptr);
    k_fill<<<ebl, 256, 0, stream>>>(ei, rowptr, cursor, colsrc);

    const float* f = x;
    float* hb[2] = {bufA, bufB};
    for (int L = 0; L < NL; ++L) {
        float* tbuf = hb[L & 1];
        const float* lstats = (L == 0) ? nullptr : (stats + (L - 1) * 256);
        const float* lg = (L == 0) ? nullptr : (bn_g + (L - 1) * 128);
        const float* lb = (L == 0) ? nullptr : (bn_b + (L - 1) * 128);
        k_agg<<<(NN + 3) / 4, 256, 0, stream>>>(f, rowptr, colsrc, lstats, lg, lb, tbuf);
        k_conv<<<(NN + 63) / 64, 256, 0, stream>>>(tbuf, conv_w + L * 16384, conv_b + L * 128,
                                                   tbuf, stats + L * 256);
        f = tbuf;
    }
    k_pool<<<NG, 256, 0, stream>>>(f, batch, stats + 5 * 256, bn_g + 5 * 128, bn_b + 5 * 128, pooled);
    k_head<<<NG, 64, 0, stream>>>(pooled, l1w, l1b, l2w, l2b, out);
}

// Round 2
// 2676.821 us; speedup vs baseline: 1.0326x; 1.0326x over previous
//
#include <hip/hip_runtime.h>
#include <math.h>

#define NN 100000
#define NE 600000
#define NG 64
#define HD 128
#define NL 6

// ---------------- CSR build ----------------

__global__ __launch_bounds__(256) void k_hist(const int* __restrict__ ei, int* __restrict__ counts) {
    int e = blockIdx.x * 256 + threadIdx.x;
    if (e < NE) atomicAdd(&counts[ei[NE + e]], 1);
}

__global__ __launch_bounds__(256) void k_scan1(const int* __restrict__ counts, int* __restrict__ bsums) {
    __shared__ int s[256];
    int i = blockIdx.x * 256 + threadIdx.x;
    s[threadIdx.x] = (i < NN) ? counts[i] : 0;
    __syncthreads();
    for (int off = 128; off > 0; off >>= 1) {
        if (threadIdx.x < off) s[threadIdx.x] += s[threadIdx.x + off];
        __syncthreads();
    }
    if (threadIdx.x == 0) bsums[blockIdx.x] = s[0];
}

__global__ __launch_bounds__(512) void k_scan2(int* __restrict__ bsums, int nb) {
    __shared__ int s[512];
    int t = threadIdx.x;
    s[t] = (t < nb) ? bsums[t] : 0;
    __syncthreads();
    for (int off = 1; off < 512; off <<= 1) {
        int v = (t >= off) ? s[t - off] : 0;
        __syncthreads();
        s[t] += v;
        __syncthreads();
    }
    if (t < nb) bsums[t] = (t == 0) ? 0 : s[t - 1];
}

__global__ __launch_bounds__(256) void k_scan3(const int* __restrict__ counts, const int* __restrict__ bsums,
                                               int* __restrict__ rowptr) {
    __shared__ int s[256];
    int t = threadIdx.x;
    int i = blockIdx.x * 256 + t;
    int v = (i < NN) ? counts[i] : 0;
    s[t] = v;
    __syncthreads();
    for (int off = 1; off < 256; off <<= 1) {
        int u = (t >= off) ? s[t - off] : 0;
        __syncthreads();
        s[t] += u;
        __syncthreads();
    }
    if (i < NN) rowptr[i] = bsums[blockIdx.x] + s[t] - v;
    if (i == 0) rowptr[NN] = NE;
}

__global__ __launch_bounds__(256) void k_fill(const int* __restrict__ ei, const int* __restrict__ rowptr,
                                              int* __restrict__ cursor, int* __restrict__ colsrc) {
    int e = blockIdx.x * 256 + threadIdx.x;
    if (e < NE) {
        int d = ei[NE + e];
        int pos = rowptr[d] + atomicAdd(&cursor[d], 1);
        colsrc[pos] = ei[e];
    }
}

// ---------------- Aggregation (one wave per node) ----------------
// t[n] = scale .* (sum of f[src] over in-edges) + deg(n) * shift
// scale/shift derived on the fly from prev layer's BN stats; identity for layer 0.

__global__ __launch_bounds__(256) void k_agg(
    const float* __restrict__ f, const int* __restrict__ rowptr,
    const int* __restrict__ colsrc, const float* __restrict__ stats,
    const float* __restrict__ bng, const float* __restrict__ bnb,
    float* __restrict__ tout) {
    int n = (blockIdx.x * 256 + threadIdx.x) >> 6;
    int lane = threadIdx.x & 63;
    if (n >= NN) return;
    int beg = rowptr[n], end = rowptr[n + 1];
    const float2* f2 = (const float2*)f;
    float ax = 0.f, ay = 0.f;
    for (int e = beg; e < end; ++e) {
        int s = colsrc[e];
        float2 v = f2[(size_t)s * 64 + lane];
        ax += v.x;
        ay += v.y;
    }
    float deg = (float)(end - beg);
    float ox, oy;
    if (stats != nullptr) {
        int c0 = lane * 2;
        const float inv_n = 1.0f / (float)NN;
        float m0 = stats[c0] * inv_n, m1 = stats[c0 + 1] * inv_n;
        float var0 = fmaf(-m0, m0, stats[HD + c0] * inv_n);
        float var1 = fmaf(-m1, m1, stats[HD + c0 + 1] * inv_n);
        float sc0 = bng[c0] * rsqrtf(var0 + 1e-5f);
        float sc1 = bng[c0 + 1] * rsqrtf(var1 + 1e-5f);
        float sh0 = bnb[c0] - m0 * sc0;
        float sh1 = bnb[c0 + 1] - m1 * sc1;
        ox = fmaf(sc0, ax, deg * sh0);
        oy = fmaf(sc1, ay, deg * sh1);
    } else {
        ox = ax;
        oy = ay;
    }
    float2 o;
    o.x = ox;
    o.y = oy;
    ((float2*)tout)[(size_t)n * 64 + lane] = o;
}

// ---------------- Conv GEMM: H = relu(T @ W + b), accumulate BN stats ----------------
// 64-row tile per block. A transposed in LDS (stride 64 + XOR swizzle -> 2 lanes/bank
// on both write and read = conflict-free per m136). W staged in LDS in two 64-k
// halves (32 KB each) so the inner loop is LDS-only: per k per wave 32 FMA (64 VALU
// cyc) vs 3 ds_read_b128 (~36 LDS cyc) -> VALU-bound. Total LDS = 64 KB -> 2 blk/CU.
// In-place safe (T == Hout): A fully staged to LDS before any store.

__global__ __launch_bounds__(256) void k_conv(
    const float* T, const float* __restrict__ W,
    const float* __restrict__ bias, float* Hout,
    float* __restrict__ stats) {
    __shared__ float At[128 * 64];   // [k][r^swz]
    __shared__ float Ws[64 * 128];   // [kk][c]
    int t = threadIdx.x;
    int row0 = blockIdx.x * 64;
    // stage 64 rows x 128 cols of A, transposed with XOR swizzle
    #pragma unroll
    for (int it = 0; it < 8; ++it) {
        int u = t + 256 * it;
        int l = u & 63;
        int gn = u >> 6;
        int r = 8 * (gn & 7) + (l >> 3);
        int k4 = 8 * (gn >> 3) + (l & 7);
        float4 v = make_float4(0.f, 0.f, 0.f, 0.f);
        int row = row0 + r;
        if (row < NN) v = ((const float4*)T)[(size_t)row * 32 + k4];
        int k = 4 * k4;
        int rs = r ^ (8 * (k4 & 7));
        At[(k + 0) * 64 + rs] = v.x;
        At[(k + 1) * 64 + rs] = v.y;
        At[(k + 2) * 64 + rs] = v.z;
        At[(k + 3) * 64 + rs] = v.w;
    }

    int rg = t & 15, cg = t >> 4;
    int r0 = 4 * rg, c0 = 8 * cg;
    float acc[4][8];
    #pragma unroll
    for (int i = 0; i < 4; ++i)
        #pragma unroll
        for (int j = 0; j < 8; ++j) acc[i][j] = 0.f;

    #pragma unroll
    for (int half = 0; half < 2; ++half) {
        if (half) __syncthreads();  // previous half's Ws reads done before overwrite
        // stage Ws = W[half*64 .. half*64+63][0..127]
        const float4* Wh = (const float4*)(W + half * 64 * 128);
        #pragma unroll
        for (int it = 0; it < 8; ++it) {
            int id = t + 256 * it;
            ((float4*)Ws)[id] = Wh[id];
        }
        __syncthreads();
        #pragma unroll 4
        for (int kk = 0; kk < 64; ++kk) {
            int k = half * 64 + kk;
            float4 a = *(const float4*)&At[k * 64 + (r0 ^ (8 * ((k >> 2) & 7)))];
            const float4* wp = (const float4*)&Ws[kk * 128 + c0];
            float4 w0 = wp[0];
            float4 w1 = wp[1];
            float av[4] = {a.x, a.y, a.z, a.w};
            float wv[8] = {w0.x, w0.y, w0.z, w0.w, w1.x, w1.y, w1.z, w1.w};
            #pragma unroll
            for (int i = 0; i < 4; ++i)
                #pragma unroll
                for (int j = 0; j < 8; ++j) acc[i][j] = fmaf(av[i], wv[j], acc[i][j]);
        }
    }

    float bsv[8];
    #pragma unroll
    for (int j = 0; j < 8; ++j) bsv[j] = bias[c0 + j];
    float lsum[8], lsq[8];
    #pragma unroll
    for (int j = 0; j < 8; ++j) { lsum[j] = 0.f; lsq[j] = 0.f; }
    #pragma unroll
    for (int i = 0; i < 4; ++i) {
        int row = row0 + r0 + i;
        if (row < NN) {
            float vals[8];
            #pragma unroll
            for (int j = 0; j < 8; ++j) {
                float v = fmaxf(acc[i][j] + bsv[j], 0.f);
                vals[j] = v;
                lsum[j] += v;
                lsq[j] = fmaf(v, v, lsq[j]);
            }
            float4* dst = (float4*)&Hout[(size_t)row * 128 + c0];
            dst[0] = make_float4(vals[0], vals[1], vals[2], vals[3]);
            dst[1] = make_float4(vals[4], vals[5], vals[6], vals[7]);
        }
    }
    // reduce across the 16 rg-lanes (lane bits 0..3), then one atomic row per block
    #pragma unroll
    for (int off = 1; off < 16; off <<= 1) {
        #pragma unroll
        for (int j = 0; j < 8; ++j) {
            lsum[j] += __shfl_xor(lsum[j], off, 64);
            lsq[j] += __shfl_xor(lsq[j], off, 64);
        }
    }
    if (rg == 0) {
        #pragma unroll
        for (int j = 0; j < 8; ++j) {
            atomicAdd(&stats[c0 + j], lsum[j]);
            atomicAdd(&stats[HD + c0 + j], lsq[j]);
        }
    }
}

// ---------------- Pooling (one block per graph; batch is sorted) ----------------

__device__ __forceinline__ int lowerb(const int* __restrict__ b, int n, int key) {
    int lo = 0, hi = n;
    while (lo < hi) {
        int mid = (lo + hi) >> 1;
        if (b[mid] < key) lo = mid + 1;
        else hi = mid;
    }
    return lo;
}

__global__ __launch_bounds__(256) void k_pool(
    const float* __restrict__ h, const int* __restrict__ batch,
    const float* __restrict__ stats, const float* __restrict__ bng, const float* __restrict__ bnb,
    float* __restrict__ pooled) {
    int g = blockIdx.x;
    int lo = lowerb(batch, NN, g);
    int hi = lowerb(batch, NN, g + 1);
    int wave = threadIdx.x >> 6, lane = threadIdx.x & 63;
    const float2* h2 = (const float2*)h;
    float ax = 0.f, ay = 0.f;
    for (int n = lo + wave; n < hi; n += 4) {
        float2 v = h2[(size_t)n * 64 + lane];
        ax += v.x;
        ay += v.y;
    }
    __shared__ float2 red[4][64];
    red[wave][lane] = make_float2(ax, ay);
    __syncthreads();
    if (wave == 0) {
        float sx = 0.f, sy = 0.f;
        for (int w = 0; w < 4; ++w) {
            sx += red[w][lane].x;
            sy += red[w][lane].y;
        }
        int cnt = hi - lo;
        int c0 = lane * 2;
        const float inv_n = 1.0f / (float)NN;
        float m0 = stats[c0] * inv_n, m1 = stats[c0 + 1] * inv_n;
        float var0 = fmaf(-m0, m0, stats[HD + c0] * inv_n);
        float var1 = fmaf(-m1, m1, stats[HD + c0 + 1] * inv_n);
        float sc0 = bng[c0] * rsqrtf(var0 + 1e-5f);
        float sc1 = bng[c0 + 1] * rsqrtf(var1 + 1e-5f);
        float sh0 = bnb[c0] - m0 * sc0;
        float sh1 = bnb[c0 + 1] - m1 * sc1;
        float denom = fmaxf((float)cnt, 1.f);
        float2 o;
        o.x = (sc0 * sx + (float)cnt * sh0) / denom;
        o.y = (sc1 * sy + (float)cnt * sh1) / denom;
        ((float2*)pooled)[g * 64 + lane] = o;
    }
}

// ---------------- MLP head + log_softmax (one wave per graph) ----------------

__global__ __launch_bounds__(64) void k_head(
    const float* __restrict__ pooled, const float* __restrict__ w1, const float* __restrict__ b1,
    const float* __restrict__ w2, const float* __restrict__ b2, float* __restrict__ out) {
    int g = blockIdx.x;
    int j = threadIdx.x;  // 0..63
    float hid = b1[j];
    const float* p = pooled + g * 128;
    #pragma unroll 8
    for (int k = 0; k < 128; ++k) hid = fmaf(p[k], w1[k * 64 + j], hid);
    float o[4];
    #pragma unroll
    for (int c = 0; c < 4; ++c) {
        float v = hid * w2[j * 4 + c];
        #pragma unroll
        for (int off = 1; off < 64; off <<= 1) v += __shfl_xor(v, off, 64);
        o[c] = v + b2[c];
    }
    if (j == 0) {
        float mx = fmaxf(fmaxf(o[0], o[1]), fmaxf(o[2], o[3]));
        float se = expf(o[0] - mx) + expf(o[1] - mx) + expf(o[2] - mx) + expf(o[3] - mx);
        float ls = mx + logf(se);
        #pragma unroll
        for (int c = 0; c < 4; ++c) out[g * 4 + c] = o[c] - ls;
    }
}

extern "C" void kernel_launch(void* const* d_in, const int* in_sizes, int n_in,
                              void* d_out, int out_size, void* d_ws, size_t ws_size,
                              hipStream_t stream) {
    const float* x = (const float*)d_in[0];
    const int* ei = (const int*)d_in[1];
    const int* batch = (const int*)d_in[2];
    const float* conv_w = (const float*)d_in[3];
    const float* conv_b = (const float*)d_in[4];
    const float* bn_g = (const float*)d_in[5];
    const float* bn_b = (const float*)d_in[6];
    const float* l1w = (const float*)d_in[7];
    const float* l1b = (const float*)d_in[8];
    const float* l2w = (const float*)d_in[9];
    const float* l2b = (const float*)d_in[10];
    float* out = (float*)d_out;
    (void)in_sizes; (void)n_in; (void)out_size; (void)ws_size;

    char* ws = (char*)d_ws;
    int* counts = (int*)(ws + 0);             // 400000 B
    int* cursor = (int*)(ws + 400000);        // 400000 B
    float* stats = (float*)(ws + 800000);     // 6*256 floats = 6144 B
    const size_t zero_bytes = 806144;         // counts + cursor + stats
    int* rowptr = (int*)(ws + 806144);        // 100001 ints
    int* bsums = (int*)(ws + 1206400);        // 391 ints
    int* colsrc = (int*)(ws + 1208192);       // 600000 ints
    float* pooled = (float*)(ws + 3608192);   // 64*128 floats
    float* bufA = (float*)(ws + 3641344);     // 51200000 B (512-aligned)
    float* bufB = (float*)(ws + 54841344);    // 51200000 B (512-aligned)

    hipMemsetAsync(ws, 0, zero_bytes, stream);

    int ebl = (NE + 255) / 256;
    int nb1 = (NN + 255) / 256;  // 391
    k_hist<<<ebl, 256, 0, stream>>>(ei, counts);
    k_scan1<<<nb1, 256, 0, stream>>>(counts, bsums);
    k_scan2<<<1, 512, 0, stream>>>(bsums, nb1);
    k_scan3<<<nb1, 256, 0, stream>>>(counts, bsums, rowptr);
    k_fill<<<ebl, 256, 0, stream>>>(ei, rowptr, cursor, colsrc);

    const float* f = x;
    float* hb[2] = {bufA, bufB};
    for (int L = 0; L < NL; ++L) {
        float* tbuf = hb[L & 1];
        const float* lstats = (L == 0) ? nullptr : (stats + (L - 1) * 256);
        const float* lg = (L == 0) ? nullptr : (bn_g + (L - 1) * 128);
        const float* lb = (L == 0) ? nullptr : (bn_b + (L - 1) * 128);
        k_agg<<<(NN + 3) / 4, 256, 0, stream>>>(f, rowptr, colsrc, lstats, lg, lb, tbuf);
        k_conv<<<(NN + 63) / 64, 256, 0, stream>>>(tbuf, conv_w + L * 16384, conv_b + L * 128,
                                                   tbuf, stats + L * 256);
        f = tbuf;
    }
    k_pool<<<NG, 256, 0, stream>>>(f, batch, stats + 5 * 256, bn_g + 5 * 128, bn_b + 5 * 128, pooled);
    k_head<<<NG, 64, 0, stream>>>(pooled, l1w, l1b, l2w, l2b, out);
}

// Round 3
// 1252.995 us; speedup vs baseline: 2.2061x; 2.1363x over previous
//
#include <hip/hip_runtime.h>
#include <math.h>

#define NN 100000
#define NE 600000
#define NG 64
#define HD 128
#define NL 6
#define NB 1563   // conv blocks = ceil(NN/64)

// ---------------- CSR build ----------------

__global__ __launch_bounds__(256) void k_hist(const int* __restrict__ ei, int* __restrict__ counts) {
    int e = blockIdx.x * 256 + threadIdx.x;
    if (e < NE) atomicAdd(&counts[ei[NE + e]], 1);
}

__global__ __launch_bounds__(256) void k_scan1(const int* __restrict__ counts, int* __restrict__ bsums) {
    __shared__ int s[256];
    int i = blockIdx.x * 256 + threadIdx.x;
    s[threadIdx.x] = (i < NN) ? counts[i] : 0;
    __syncthreads();
    for (int off = 128; off > 0; off >>= 1) {
        if (threadIdx.x < off) s[threadIdx.x] += s[threadIdx.x + off];
        __syncthreads();
    }
    if (threadIdx.x == 0) bsums[blockIdx.x] = s[0];
}

__global__ __launch_bounds__(512) void k_scan2(int* __restrict__ bsums, int nb) {
    __shared__ int s[512];
    int t = threadIdx.x;
    s[t] = (t < nb) ? bsums[t] : 0;
    __syncthreads();
    for (int off = 1; off < 512; off <<= 1) {
        int v = (t >= off) ? s[t - off] : 0;
        __syncthreads();
        s[t] += v;
        __syncthreads();
    }
    if (t < nb) bsums[t] = (t == 0) ? 0 : s[t - 1];
}

__global__ __launch_bounds__(256) void k_scan3(const int* __restrict__ counts, const int* __restrict__ bsums,
                                               int* __restrict__ rowptr) {
    __shared__ int s[256];
    int t = threadIdx.x;
    int i = blockIdx.x * 256 + t;
    int v = (i < NN) ? counts[i] : 0;
    s[t] = v;
    __syncthreads();
    for (int off = 1; off < 256; off <<= 1) {
        int u = (t >= off) ? s[t - off] : 0;
        __syncthreads();
        s[t] += u;
        __syncthreads();
    }
    if (i < NN) rowptr[i] = bsums[blockIdx.x] + s[t] - v;
    if (i == 0) rowptr[NN] = NE;
}

__global__ __launch_bounds__(256) void k_fill(const int* __restrict__ ei, const int* __restrict__ rowptr,
                                              int* __restrict__ cursor, int* __restrict__ colsrc) {
    int e = blockIdx.x * 256 + threadIdx.x;
    if (e < NE) {
        int d = ei[NE + e];
        int pos = rowptr[d] + atomicAdd(&cursor[d], 1);
        colsrc[pos] = ei[e];
    }
}

// ---------------- Aggregation (one wave per node) ----------------

__global__ __launch_bounds__(256) void k_agg(
    const float* __restrict__ f, const int* __restrict__ rowptr,
    const int* __restrict__ colsrc, const float* __restrict__ stats,
    const float* __restrict__ bng, const float* __restrict__ bnb,
    float* __restrict__ tout) {
    int n = (blockIdx.x * 256 + threadIdx.x) >> 6;
    int lane = threadIdx.x & 63;
    if (n >= NN) return;
    int beg = rowptr[n], end = rowptr[n + 1];
    const float2* f2 = (const float2*)f;
    float ax = 0.f, ay = 0.f;
    for (int e = beg; e < end; ++e) {
        int s = colsrc[e];
        float2 v = f2[(size_t)s * 64 + lane];
        ax += v.x;
        ay += v.y;
    }
    float deg = (float)(end - beg);
    float ox, oy;
    if (stats != nullptr) {
        int c0 = lane * 2;
        const float inv_n = 1.0f / (float)NN;
        float m0 = stats[c0] * inv_n, m1 = stats[c0 + 1] * inv_n;
        float var0 = fmaf(-m0, m0, stats[HD + c0] * inv_n);
        float var1 = fmaf(-m1, m1, stats[HD + c0 + 1] * inv_n);
        float sc0 = bng[c0] * rsqrtf(var0 + 1e-5f);
        float sc1 = bng[c0 + 1] * rsqrtf(var1 + 1e-5f);
        float sh0 = bnb[c0] - m0 * sc0;
        float sh1 = bnb[c0 + 1] - m1 * sc1;
        ox = fmaf(sc0, ax, deg * sh0);
        oy = fmaf(sc1, ay, deg * sh1);
    } else {
        ox = ax;
        oy = ay;
    }
    float2 o;
    o.x = ox;
    o.y = oy;
    ((float2*)tout)[(size_t)n * 64 + lane] = o;
}

// ---------------- Conv GEMM: H = relu(T @ W + b), per-block BN partials ----------------
// 64-row tile per block. A transposed in LDS (stride 64 + XOR swizzle). W staged in
// LDS in two 64-k halves. NO global atomics: per-block stats partials stored
// non-atomically to partials[bid][256]; k_red reduces them afterward.

__global__ __launch_bounds__(256) void k_conv(
    const float* T, const float* __restrict__ W,
    const float* __restrict__ bias, float* Hout,
    float* __restrict__ partials) {
    __shared__ float At[128 * 64];   // [k][r^swz]
    __shared__ float Ws[64 * 128];   // [kk][c]
    int t = threadIdx.x;
    int row0 = blockIdx.x * 64;
    #pragma unroll
    for (int it = 0; it < 8; ++it) {
        int u = t + 256 * it;
        int l = u & 63;
        int gn = u >> 6;
        int r = 8 * (gn & 7) + (l >> 3);
        int k4 = 8 * (gn >> 3) + (l & 7);
        float4 v = make_float4(0.f, 0.f, 0.f, 0.f);
        int row = row0 + r;
        if (row < NN) v = ((const float4*)T)[(size_t)row * 32 + k4];
        int k = 4 * k4;
        int rs = r ^ (8 * (k4 & 7));
        At[(k + 0) * 64 + rs] = v.x;
        At[(k + 1) * 64 + rs] = v.y;
        At[(k + 2) * 64 + rs] = v.z;
        At[(k + 3) * 64 + rs] = v.w;
    }

    int rg = t & 15, cg = t >> 4;
    int r0 = 4 * rg, c0 = 8 * cg;
    float acc[4][8];
    #pragma unroll
    for (int i = 0; i < 4; ++i)
        #pragma unroll
        for (int j = 0; j < 8; ++j) acc[i][j] = 0.f;

    #pragma unroll
    for (int half = 0; half < 2; ++half) {
        if (half) __syncthreads();
        const float4* Wh = (const float4*)(W + half * 64 * 128);
        #pragma unroll
        for (int it = 0; it < 8; ++it) {
            int id = t + 256 * it;
            ((float4*)Ws)[id] = Wh[id];
        }
        __syncthreads();
        #pragma unroll 4
        for (int kk = 0; kk < 64; ++kk) {
            int k = half * 64 + kk;
            float4 a = *(const float4*)&At[k * 64 + (r0 ^ (8 * ((k >> 2) & 7)))];
            const float4* wp = (const float4*)&Ws[kk * 128 + c0];
            float4 w0 = wp[0];
            float4 w1 = wp[1];
            float av[4] = {a.x, a.y, a.z, a.w};
            float wv[8] = {w0.x, w0.y, w0.z, w0.w, w1.x, w1.y, w1.z, w1.w};
            #pragma unroll
            for (int i = 0; i < 4; ++i)
                #pragma unroll
                for (int j = 0; j < 8; ++j) acc[i][j] = fmaf(av[i], wv[j], acc[i][j]);
        }
    }

    float bsv[8];
    #pragma unroll
    for (int j = 0; j < 8; ++j) bsv[j] = bias[c0 + j];
    float lsum[8], lsq[8];
    #pragma unroll
    for (int j = 0; j < 8; ++j) { lsum[j] = 0.f; lsq[j] = 0.f; }
    #pragma unroll
    for (int i = 0; i < 4; ++i) {
        int row = row0 + r0 + i;
        if (row < NN) {
            float vals[8];
            #pragma unroll
            for (int j = 0; j < 8; ++j) {
                float v = fmaxf(acc[i][j] + bsv[j], 0.f);
                vals[j] = v;
                lsum[j] += v;
                lsq[j] = fmaf(v, v, lsq[j]);
            }
            float4* dst = (float4*)&Hout[(size_t)row * 128 + c0];
            dst[0] = make_float4(vals[0], vals[1], vals[2], vals[3]);
            dst[1] = make_float4(vals[4], vals[5], vals[6], vals[7]);
        }
    }
    // reduce across the 16 rg-lanes, then ONE non-atomic partial row per block
    #pragma unroll
    for (int off = 1; off < 16; off <<= 1) {
        #pragma unroll
        for (int j = 0; j < 8; ++j) {
            lsum[j] += __shfl_xor(lsum[j], off, 64);
            lsq[j] += __shfl_xor(lsq[j], off, 64);
        }
    }
    if (rg == 0) {
        float* pr = partials + (size_t)blockIdx.x * 256;
        float4* p0 = (float4*)&pr[c0];
        p0[0] = make_float4(lsum[0], lsum[1], lsum[2], lsum[3]);
        p0[1] = make_float4(lsum[4], lsum[5], lsum[6], lsum[7]);
        float4* p1 = (float4*)&pr[HD + c0];
        p1[0] = make_float4(lsq[0], lsq[1], lsq[2], lsq[3]);
        p1[1] = make_float4(lsq[4], lsq[5], lsq[6], lsq[7]);
    }
}

// ---------------- Partial-stats reduction: 1563 x 256 -> 256 ----------------
// 16 blocks x 256 threads; coalesced rows; 4096 well-spread atomics total.

__global__ __launch_bounds__(256) void k_red(const float* __restrict__ partials,
                                             float* __restrict__ stats) {
    int t = threadIdx.x;
    float s = 0.f;
    for (int r = blockIdx.x; r < NB; r += 16) s += partials[(size_t)r * 256 + t];
    atomicAdd(&stats[t], s);
}

// ---------------- Pooling (one block per graph; batch is sorted) ----------------

__device__ __forceinline__ int lowerb(const int* __restrict__ b, int n, int key) {
    int lo = 0, hi = n;
    while (lo < hi) {
        int mid = (lo + hi) >> 1;
        if (b[mid] < key) lo = mid + 1;
        else hi = mid;
    }
    return lo;
}

__global__ __launch_bounds__(256) void k_pool(
    const float* __restrict__ h, const int* __restrict__ batch,
    const float* __restrict__ stats, const float* __restrict__ bng, const float* __restrict__ bnb,
    float* __restrict__ pooled) {
    int g = blockIdx.x;
    int lo = lowerb(batch, NN, g);
    int hi = lowerb(batch, NN, g + 1);
    int wave = threadIdx.x >> 6, lane = threadIdx.x & 63;
    const float2* h2 = (const float2*)h;
    float ax = 0.f, ay = 0.f;
    for (int n = lo + wave; n < hi; n += 4) {
        float2 v = h2[(size_t)n * 64 + lane];
        ax += v.x;
        ay += v.y;
    }
    __shared__ float2 red[4][64];
    red[wave][lane] = make_float2(ax, ay);
    __syncthreads();
    if (wave == 0) {
        float sx = 0.f, sy = 0.f;
        for (int w = 0; w < 4; ++w) {
            sx += red[w][lane].x;
            sy += red[w][lane].y;
        }
        int cnt = hi - lo;
        int c0 = lane * 2;
        const float inv_n = 1.0f / (float)NN;
        float m0 = stats[c0] * inv_n, m1 = stats[c0 + 1] * inv_n;
        float var0 = fmaf(-m0, m0, stats[HD + c0] * inv_n);
        float var1 = fmaf(-m1, m1, stats[HD + c0 + 1] * inv_n);
        float sc0 = bng[c0] * rsqrtf(var0 + 1e-5f);
        float sc1 = bng[c0 + 1] * rsqrtf(var1 + 1e-5f);
        float sh0 = bnb[c0] - m0 * sc0;
        float sh1 = bnb[c0 + 1] - m1 * sc1;
        float denom = fmaxf((float)cnt, 1.f);
        float2 o;
        o.x = (sc0 * sx + (float)cnt * sh0) / denom;
        o.y = (sc1 * sy + (float)cnt * sh1) / denom;
        ((float2*)pooled)[g * 64 + lane] = o;
    }
}

// ---------------- MLP head + log_softmax (one wave per graph) ----------------

__global__ __launch_bounds__(64) void k_head(
    const float* __restrict__ pooled, const float* __restrict__ w1, const float* __restrict__ b1,
    const float* __restrict__ w2, const float* __restrict__ b2, float* __restrict__ out) {
    int g = blockIdx.x;
    int j = threadIdx.x;  // 0..63
    float hid = b1[j];
    const float* p = pooled + g * 128;
    #pragma unroll 8
    for (int k = 0; k < 128; ++k) hid = fmaf(p[k], w1[k * 64 + j], hid);
    float o[4];
    #pragma unroll
    for (int c = 0; c < 4; ++c) {
        float v = hid * w2[j * 4 + c];
        #pragma unroll
        for (int off = 1; off < 64; off <<= 1) v += __shfl_xor(v, off, 64);
        o[c] = v + b2[c];
    }
    if (j == 0) {
        float mx = fmaxf(fmaxf(o[0], o[1]), fmaxf(o[2], o[3]));
        float se = expf(o[0] - mx) + expf(o[1] - mx) + expf(o[2] - mx) + expf(o[3] - mx);
        float ls = mx + logf(se);
        #pragma unroll
        for (int c = 0; c < 4; ++c) out[g * 4 + c] = o[c] - ls;
    }
}

extern "C" void kernel_launch(void* const* d_in, const int* in_sizes, int n_in,
                              void* d_out, int out_size, void* d_ws, size_t ws_size,
                              hipStream_t stream) {
    const float* x = (const float*)d_in[0];
    const int* ei = (const int*)d_in[1];
    const int* batch = (const int*)d_in[2];
    const float* conv_w = (const float*)d_in[3];
    const float* conv_b = (const float*)d_in[4];
    const float* bn_g = (const float*)d_in[5];
    const float* bn_b = (const float*)d_in[6];
    const float* l1w = (const float*)d_in[7];
    const float* l1b = (const float*)d_in[8];
    const float* l2w = (const float*)d_in[9];
    const float* l2b = (const float*)d_in[10];
    float* out = (float*)d_out;
    (void)in_sizes; (void)n_in; (void)out_size; (void)ws_size;

    char* ws = (char*)d_ws;
    int* counts = (int*)(ws + 0);             // 400000 B
    int* cursor = (int*)(ws + 400000);        // 400000 B
    float* stats = (float*)(ws + 800000);     // 6*256 floats = 6144 B
    const size_t zero_bytes = 806144;         // counts + cursor + stats
    int* rowptr = (int*)(ws + 806144);        // 100001 ints
    int* bsums = (int*)(ws + 1206400);        // 391 ints
    int* colsrc = (int*)(ws + 1208192);       // 600000 ints
    float* pooled = (float*)(ws + 3608192);   // 64*128 floats
    float* bufA = (float*)(ws + 3641344);     // 51200000 B (512-aligned)
    float* bufB = (float*)(ws + 54841344);    // 51200000 B (512-aligned)

    hipMemsetAsync(ws, 0, zero_bytes, stream);

    int ebl = (NE + 255) / 256;
    int nb1 = (NN + 255) / 256;  // 391
    k_hist<<<ebl, 256, 0, stream>>>(ei, counts);
    k_scan1<<<nb1, 256, 0, stream>>>(counts, bsums);
    k_scan2<<<1, 512, 0, stream>>>(bsums, nb1);
    k_scan3<<<nb1, 256, 0, stream>>>(counts, bsums, rowptr);
    k_fill<<<ebl, 256, 0, stream>>>(ei, rowptr, cursor, colsrc);

    const float* f = x;
    float* hb[2] = {bufA, bufB};
    for (int L = 0; L < NL; ++L) {
        float* tbuf = hb[L & 1];
        // partials live in the OTHER ping-pong buffer, which is dead during
        // k_conv(L)/k_red(L): its old contents (f of layer L) were fully consumed
        // by k_agg(L), and k_agg(L+1) overwrites it only after k_red(L).
        float* partials = hb[1 - (L & 1)];
        const float* lstats = (L == 0) ? nullptr : (stats + (L - 1) * 256);
        const float* lg = (L == 0) ? nullptr : (bn_g + (L - 1) * 128);
        const float* lb = (L == 0) ? nullptr : (bn_b + (L - 1) * 128);
        k_agg<<<(NN + 3) / 4, 256, 0, stream>>>(f, rowptr, colsrc, lstats, lg, lb, tbuf);
        k_conv<<<NB, 256, 0, stream>>>(tbuf, conv_w + L * 16384, conv_b + L * 128,
                                       tbuf, partials);
        k_red<<<16, 256, 0, stream>>>(partials, stats + L * 256);
        f = tbuf;
    }
    k_pool<<<NG, 256, 0, stream>>>(f, batch, stats + 5 * 256, bn_g + 5 * 128, bn_b + 5 * 128, pooled);
    k_head<<<NG, 64, 0, stream>>>(pooled, l1w, l1b, l2w, l2b, out);
}

// Round 5
// 1051.079 us; speedup vs baseline: 2.6299x; 1.1921x over previous
//
#include <hip/hip_runtime.h>
#include <math.h>

#define NN 100000
#define NE 600000
#define NG 64
#define HD 128
#define NL 6
#define NB 1563   // conv blocks = ceil(NN/64)
#define PSL 16    // pool slices per graph

// ---------------- CSR build ----------------

__global__ __launch_bounds__(256) void k_hist(const int* __restrict__ ei, int* __restrict__ counts) {
    int e = blockIdx.x * 256 + threadIdx.x;
    if (e < NE) atomicAdd(&counts[ei[NE + e]], 1);
}

__global__ __launch_bounds__(256) void k_scan1(const int* __restrict__ counts, int* __restrict__ bsums) {
    __shared__ int s[256];
    int i = blockIdx.x * 256 + threadIdx.x;
    s[threadIdx.x] = (i < NN) ? counts[i] : 0;
    __syncthreads();
    for (int off = 128; off > 0; off >>= 1) {
        if (threadIdx.x < off) s[threadIdx.x] += s[threadIdx.x + off];
        __syncthreads();
    }
    if (threadIdx.x == 0) bsums[blockIdx.x] = s[0];
}

__global__ __launch_bounds__(512) void k_scan2(int* __restrict__ bsums, int nb) {
    __shared__ int s[512];
    int t = threadIdx.x;
    s[t] = (t < nb) ? bsums[t] : 0;
    __syncthreads();
    for (int off = 1; off < 512; off <<= 1) {
        int v = (t >= off) ? s[t - off] : 0;
        __syncthreads();
        s[t] += v;
        __syncthreads();
    }
    if (t < nb) bsums[t] = (t == 0) ? 0 : s[t - 1];
}

__global__ __launch_bounds__(256) void k_scan3(const int* __restrict__ counts, const int* __restrict__ bsums,
                                               int* __restrict__ rowptr) {
    __shared__ int s[256];
    int t = threadIdx.x;
    int i = blockIdx.x * 256 + t;
    int v = (i < NN) ? counts[i] : 0;
    s[t] = v;
    __syncthreads();
    for (int off = 1; off < 256; off <<= 1) {
        int u = (t >= off) ? s[t - off] : 0;
        __syncthreads();
        s[t] += u;
        __syncthreads();
    }
    if (i < NN) rowptr[i] = bsums[blockIdx.x] + s[t] - v;
    if (i == 0) rowptr[NN] = NE;
}

__global__ __launch_bounds__(256) void k_fill(const int* __restrict__ ei, const int* __restrict__ rowptr,
                                              int* __restrict__ cursor, int* __restrict__ colsrc) {
    int e = blockIdx.x * 256 + threadIdx.x;
    if (e < NE) {
        int d = ei[NE + e];
        int pos = rowptr[d] + atomicAdd(&cursor[d], 1);
        colsrc[pos] = ei[e];
    }
}

// ---------------- Aggregation (one wave per node) ----------------
// 4-way unrolled edge loop: four independent colsrc->row gather chains in flight.

__global__ __launch_bounds__(256) void k_agg(
    const float* __restrict__ f, const int* __restrict__ rowptr,
    const int* __restrict__ colsrc, const float* __restrict__ stats,
    const float* __restrict__ bng, const float* __restrict__ bnb,
    float* __restrict__ tout) {
    int n = (blockIdx.x * 256 + threadIdx.x) >> 6;
    int lane = threadIdx.x & 63;
    if (n >= NN) return;
    int beg = rowptr[n], end = rowptr[n + 1];
    const float2* f2 = (const float2*)f;
    float ax = 0.f, ay = 0.f;
    int e = beg;
    for (; e + 3 < end; e += 4) {
        int s0 = colsrc[e];
        int s1 = colsrc[e + 1];
        int s2 = colsrc[e + 2];
        int s3 = colsrc[e + 3];
        float2 v0 = f2[(size_t)s0 * 64 + lane];
        float2 v1 = f2[(size_t)s1 * 64 + lane];
        float2 v2 = f2[(size_t)s2 * 64 + lane];
        float2 v3 = f2[(size_t)s3 * 64 + lane];
        ax += (v0.x + v1.x) + (v2.x + v3.x);
        ay += (v0.y + v1.y) + (v2.y + v3.y);
    }
    for (; e < end; ++e) {
        int s0 = colsrc[e];
        float2 v0 = f2[(size_t)s0 * 64 + lane];
        ax += v0.x;
        ay += v0.y;
    }
    float deg = (float)(end - beg);
    float ox, oy;
    if (stats != nullptr) {
        int c0 = lane * 2;
        const float inv_n = 1.0f / (float)NN;
        float m0 = stats[c0] * inv_n, m1 = stats[c0 + 1] * inv_n;
        float var0 = fmaf(-m0, m0, stats[HD + c0] * inv_n);
        float var1 = fmaf(-m1, m1, stats[HD + c0 + 1] * inv_n);
        float sc0 = bng[c0] * rsqrtf(var0 + 1e-5f);
        float sc1 = bng[c0 + 1] * rsqrtf(var1 + 1e-5f);
        float sh0 = bnb[c0] - m0 * sc0;
        float sh1 = bnb[c0 + 1] - m1 * sc1;
        ox = fmaf(sc0, ax, deg * sh0);
        oy = fmaf(sc1, ay, deg * sh1);
    } else {
        ox = ax;
        oy = ay;
    }
    float2 o;
    o.x = ox;
    o.y = oy;
    ((float2*)tout)[(size_t)n * 64 + lane] = o;
}

// ---------------- Conv GEMM: H = relu(T @ W + b), per-block BN partials ----------------

__global__ __launch_bounds__(256) void k_conv(
    const float* T, const float* __restrict__ W,
    const float* __restrict__ bias, float* Hout,
    float* __restrict__ partials) {
    __shared__ float At[128 * 64];   // [k][r^swz]
    __shared__ float Ws[64 * 128];   // [kk][c]
    int t = threadIdx.x;
    int row0 = blockIdx.x * 64;
    #pragma unroll
    for (int it = 0; it < 8; ++it) {
        int u = t + 256 * it;
        int l = u & 63;
        int gn = u >> 6;
        int r = 8 * (gn & 7) + (l >> 3);
        int k4 = 8 * (gn >> 3) + (l & 7);
        float4 v = make_float4(0.f, 0.f, 0.f, 0.f);
        int row = row0 + r;
        if (row < NN) v = ((const float4*)T)[(size_t)row * 32 + k4];
        int k = 4 * k4;
        int rs = r ^ (8 * (k4 & 7));
        At[(k + 0) * 64 + rs] = v.x;
        At[(k + 1) * 64 + rs] = v.y;
        At[(k + 2) * 64 + rs] = v.z;
        At[(k + 3) * 64 + rs] = v.w;
    }

    int rg = t & 15, cg = t >> 4;
    int r0 = 4 * rg, c0 = 8 * cg;
    float acc[4][8];
    #pragma unroll
    for (int i = 0; i < 4; ++i)
        #pragma unroll
        for (int j = 0; j < 8; ++j) acc[i][j] = 0.f;

    #pragma unroll
    for (int half = 0; half < 2; ++half) {
        if (half) __syncthreads();
        const float4* Wh = (const float4*)(W + half * 64 * 128);
        #pragma unroll
        for (int it = 0; it < 8; ++it) {
            int id = t + 256 * it;
            ((float4*)Ws)[id] = Wh[id];
        }
        __syncthreads();
        #pragma unroll 4
        for (int kk = 0; kk < 64; ++kk) {
            int k = half * 64 + kk;
            float4 a = *(const float4*)&At[k * 64 + (r0 ^ (8 * ((k >> 2) & 7)))];
            const float4* wp = (const float4*)&Ws[kk * 128 + c0];
            float4 w0 = wp[0];
            float4 w1 = wp[1];
            float av[4] = {a.x, a.y, a.z, a.w};
            float wv[8] = {w0.x, w0.y, w0.z, w0.w, w1.x, w1.y, w1.z, w1.w};
            #pragma unroll
            for (int i = 0; i < 4; ++i)
                #pragma unroll
                for (int j = 0; j < 8; ++j) acc[i][j] = fmaf(av[i], wv[j], acc[i][j]);
        }
    }

    float bsv[8];
    #pragma unroll
    for (int j = 0; j < 8; ++j) bsv[j] = bias[c0 + j];
    float lsum[8], lsq[8];
    #pragma unroll
    for (int j = 0; j < 8; ++j) { lsum[j] = 0.f; lsq[j] = 0.f; }
    #pragma unroll
    for (int i = 0; i < 4; ++i) {
        int row = row0 + r0 + i;
        if (row < NN) {
            float vals[8];
            #pragma unroll
            for (int j = 0; j < 8; ++j) {
                float v = fmaxf(acc[i][j] + bsv[j], 0.f);
                vals[j] = v;
                lsum[j] += v;
                lsq[j] = fmaf(v, v, lsq[j]);
            }
            float4* dst = (float4*)&Hout[(size_t)row * 128 + c0];
            dst[0] = make_float4(vals[0], vals[1], vals[2], vals[3]);
            dst[1] = make_float4(vals[4], vals[5], vals[6], vals[7]);
        }
    }
    #pragma unroll
    for (int off = 1; off < 16; off <<= 1) {
        #pragma unroll
        for (int j = 0; j < 8; ++j) {
            lsum[j] += __shfl_xor(lsum[j], off, 64);
            lsq[j] += __shfl_xor(lsq[j], off, 64);
        }
    }
    if (rg == 0) {
        float* pr = partials + (size_t)blockIdx.x * 256;
        float4* p0 = (float4*)&pr[c0];
        p0[0] = make_float4(lsum[0], lsum[1], lsum[2], lsum[3]);
        p0[1] = make_float4(lsum[4], lsum[5], lsum[6], lsum[7]);
        float4* p1 = (float4*)&pr[HD + c0];
        p1[0] = make_float4(lsq[0], lsq[1], lsq[2], lsq[3]);
        p1[1] = make_float4(lsq[4], lsq[5], lsq[6], lsq[7]);
    }
}

// ---------------- Partial-stats reduction: 1563 x 256 -> 256 ----------------

__global__ __launch_bounds__(256) void k_red(const float* __restrict__ partials,
                                             float* __restrict__ stats) {
    int t = threadIdx.x;
    float s = 0.f;
    for (int r = blockIdx.x; r < NB; r += 16) s += partials[(size_t)r * 256 + t];
    atomicAdd(&stats[t], s);
}

// ---------------- Pooling, phase 1: per-(graph,slice) partial sums ----------------

__device__ __forceinline__ int lowerb(const int* __restrict__ b, int n, int key) {
    int lo = 0, hi = n;
    while (lo < hi) {
        int mid = (lo + hi) >> 1;
        if (b[mid] < key) lo = mid + 1;
        else hi = mid;
    }
    return lo;
}

__global__ __launch_bounds__(256) void k_pool1(
    const float* __restrict__ h, const int* __restrict__ batch,
    float* __restrict__ ppart) {
    int g = blockIdx.x >> 4;
    int sl = blockIdx.x & (PSL - 1);
    int lo = lowerb(batch, NN, g);
    int hi = lowerb(batch, NN, g + 1);
    int cnt = hi - lo;
    int a = lo + (int)(((long long)cnt * sl) >> 4);
    int b = lo + (int)(((long long)cnt * (sl + 1)) >> 4);
    int wave = threadIdx.x >> 6, lane = threadIdx.x & 63;
    const float2* h2 = (const float2*)h;
    float ax = 0.f, ay = 0.f;
    for (int n = a + wave; n < b; n += 4) {
        float2 v = h2[(size_t)n * 64 + lane];
        ax += v.x;
        ay += v.y;
    }
    __shared__ float2 red[4][64];
    red[wave][lane] = make_float2(ax, ay);
    __syncthreads();
    if (wave == 0) {
        float sx = 0.f, sy = 0.f;
        for (int w = 0; w < 4; ++w) {
            sx += red[w][lane].x;
            sy += red[w][lane].y;
        }
        ((float2*)ppart)[(size_t)blockIdx.x * 64 + lane] = make_float2(sx, sy);
    }
}

// ---------------- Pooling, phase 2: combine slices + deferred BN affine ----------------

__global__ __launch_bounds__(64) void k_pool2(
    const float* __restrict__ ppart, const int* __restrict__ batch,
    const float* __restrict__ stats, const float* __restrict__ bng, const float* __restrict__ bnb,
    float* __restrict__ pooled) {
    int g = blockIdx.x;
    int lane = threadIdx.x;  // 0..63
    float sx = 0.f, sy = 0.f;
    #pragma unroll
    for (int s = 0; s < PSL; ++s) {
        float2 v = ((const float2*)ppart)[(size_t)(g * PSL + s) * 64 + lane];
        sx += v.x;
        sy += v.y;
    }
    int cnt = lowerb(batch, NN, g + 1) - lowerb(batch, NN, g);
    int c0 = lane * 2;
    const float inv_n = 1.0f / (float)NN;
    float m0 = stats[c0] * inv_n, m1 = stats[c0 + 1] * inv_n;
    float var0 = fmaf(-m0, m0, stats[HD + c0] * inv_n);
    float var1 = fmaf(-m1, m1, stats[HD + c0 + 1] * inv_n);
    float sc0 = bng[c0] * rsqrtf(var0 + 1e-5f);
    float sc1 = bng[c0 + 1] * rsqrtf(var1 + 1e-5f);
    float sh0 = bnb[c0] - m0 * sc0;
    float sh1 = bnb[c0 + 1] - m1 * sc1;
    float denom = fmaxf((float)cnt, 1.f);
    float2 o;
    o.x = (sc0 * sx + (float)cnt * sh0) / denom;
    o.y = (sc1 * sy + (float)cnt * sh1) / denom;
    ((float2*)pooled)[g * 64 + lane] = o;
}

// ---------------- MLP head + log_softmax (one wave per graph) ----------------

__global__ __launch_bounds__(64) void k_head(
    const float* __restrict__ pooled, const float* __restrict__ w1, const float* __restrict__ b1,
    const float* __restrict__ w2, const float* __restrict__ b2, float* __restrict__ out) {
    int g = blockIdx.x;
    int j = threadIdx.x;  // 0..63
    float hid = b1[j];
    const float* p = pooled + g * 128;
    #pragma unroll 8
    for (int k = 0; k < 128; ++k) hid = fmaf(p[k], w1[k * 64 + j], hid);
    float o[4];
    #pragma unroll
    for (int c = 0; c < 4; ++c) {
        float v = hid * w2[j * 4 + c];
        #pragma unroll
        for (int off = 1; off < 64; off <<= 1) v += __shfl_xor(v, off, 64);
        o[c] = v + b2[c];
    }
    if (j == 0) {
        float mx = fmaxf(fmaxf(o[0], o[1]), fmaxf(o[2], o[3]));
        float se = expf(o[0] - mx) + expf(o[1] - mx) + expf(o[2] - mx) + expf(o[3] - mx);
        float ls = mx + logf(se);
        #pragma unroll
        for (int c = 0; c < 4; ++c) out[g * 4 + c] = o[c] - ls;
    }
}

extern "C" void kernel_launch(void* const* d_in, const int* in_sizes, int n_in,
                              void* d_out, int out_size, void* d_ws, size_t ws_size,
                              hipStream_t stream) {
    const float* x = (const float*)d_in[0];
    const int* ei = (const int*)d_in[1];
    const int* batch = (const int*)d_in[2];
    const float* conv_w = (const float*)d_in[3];
    const float* conv_b = (const float*)d_in[4];
    const float* bn_g = (const float*)d_in[5];
    const float* bn_b = (const float*)d_in[6];
    const float* l1w = (const float*)d_in[7];
    const float* l1b = (const float*)d_in[8];
    const float* l2w = (const float*)d_in[9];
    const float* l2b = (const float*)d_in[10];
    float* out = (float*)d_out;
    (void)in_sizes; (void)n_in; (void)out_size; (void)ws_size;

    char* ws = (char*)d_ws;
    int* counts = (int*)(ws + 0);             // 400000 B
    int* cursor = (int*)(ws + 400000);        // 400000 B
    float* stats = (float*)(ws + 800000);     // 6*256 floats = 6144 B
    const size_t zero_bytes = 806144;         // counts + cursor + stats
    int* rowptr = (int*)(ws + 806144);        // 100001 ints
    int* bsums = (int*)(ws + 1206400);        // 391 ints
    int* colsrc = (int*)(ws + 1208192);       // 600000 ints
    float* pooled = (float*)(ws + 3608192);   // 64*128 floats
    float* bufA = (float*)(ws + 3641344);     // 51200000 B (512-aligned)
    float* bufB = (float*)(ws + 54841344);    // 51200000 B (512-aligned)

    hipMemsetAsync(ws, 0, zero_bytes, stream);

    int ebl = (NE + 255) / 256;
    int nb1 = (NN + 255) / 256;  // 391
    k_hist<<<ebl, 256, 0, stream>>>(ei, counts);
    k_scan1<<<nb1, 256, 0, stream>>>(counts, bsums);
    k_scan2<<<1, 512, 0, stream>>>(bsums, nb1);
    k_scan3<<<nb1, 256, 0, stream>>>(counts, bsums, rowptr);
    k_fill<<<ebl, 256, 0, stream>>>(ei, rowptr, cursor, colsrc);

    const float* f = x;
    float* hb[2] = {bufA, bufB};
    for (int L = 0; L < NL; ++L) {
        float* tbuf = hb[L & 1];
        float* partials = hb[1 - (L & 1)];  // dead buffer during conv/red
        const float* lstats = (L == 0) ? nullptr : (stats + (L - 1) * 256);
        const float* lg = (L == 0) ? nullptr : (bn_g + (L - 1) * 128);
        const float* lb = (L == 0) ? nullptr : (bn_b + (L - 1) * 128);
        k_agg<<<(NN + 3) / 4, 256, 0, stream>>>(f, rowptr, colsrc, lstats, lg, lb, tbuf);
        k_conv<<<NB, 256, 0, stream>>>(tbuf, conv_w + L * 16384, conv_b + L * 128,
                                       tbuf, partials);
        k_red<<<16, 256, 0, stream>>>(partials, stats + L * 256);
        f = tbuf;
    }
    // final h is in bufB (L=5 odd); bufA is dead -> reuse for pool partials
    float* ppart = hb[0];
    k_pool1<<<NG * PSL, 256, 0, stream>>>(f, batch, ppart);
    k_pool2<<<NG, 64, 0, stream>>>(ppart, batch, stats + 5 * 256, bn_g + 5 * 128, bn_b + 5 * 128, pooled);
    k_head<<<NG, 64, 0, stream>>>(pooled, l1w, l1b, l2w, l2b, out);
}

// Round 6
// 992.932 us; speedup vs baseline: 2.7839x; 1.0586x over previous
//
#include <hip/hip_runtime.h>
#include <math.h>

#define NN 100000
#define NE 600000
#define NG 64
#define HD 128
#define NL 6
#define NB 1563   // conv blocks = ceil(NN/64)
#define PSL 16    // pool slices per graph

typedef unsigned short ushort_t;

__device__ __forceinline__ float bf2f(ushort_t u) {
    return __uint_as_float(((unsigned)u) << 16);
}
__device__ __forceinline__ ushort_t f2bf(float f) {
    unsigned u = __float_as_uint(f);
    unsigned r = (u + 0x7fffu + ((u >> 16) & 1u)) >> 16;   // round-to-nearest-even
    return (ushort_t)r;
}

// ---------------- CSR build ----------------

__global__ __launch_bounds__(256) void k_hist(const int* __restrict__ ei, int* __restrict__ counts) {
    int e = blockIdx.x * 256 + threadIdx.x;
    if (e < NE) atomicAdd(&counts[ei[NE + e]], 1);
}

__global__ __launch_bounds__(256) void k_scan1(const int* __restrict__ counts, int* __restrict__ bsums) {
    __shared__ int s[256];
    int i = blockIdx.x * 256 + threadIdx.x;
    s[threadIdx.x] = (i < NN) ? counts[i] : 0;
    __syncthreads();
    for (int off = 128; off > 0; off >>= 1) {
        if (threadIdx.x < off) s[threadIdx.x] += s[threadIdx.x + off];
        __syncthreads();
    }
    if (threadIdx.x == 0) bsums[blockIdx.x] = s[0];
}

__global__ __launch_bounds__(512) void k_scan2(int* __restrict__ bsums, int nb) {
    __shared__ int s[512];
    int t = threadIdx.x;
    s[t] = (t < nb) ? bsums[t] : 0;
    __syncthreads();
    for (int off = 1; off < 512; off <<= 1) {
        int v = (t >= off) ? s[t - off] : 0;
        __syncthreads();
        s[t] += v;
        __syncthreads();
    }
    if (t < nb) bsums[t] = (t == 0) ? 0 : s[t - 1];
}

__global__ __launch_bounds__(256) void k_scan3(const int* __restrict__ counts, const int* __restrict__ bsums,
                                               int* __restrict__ rowptr) {
    __shared__ int s[256];
    int t = threadIdx.x;
    int i = blockIdx.x * 256 + t;
    int v = (i < NN) ? counts[i] : 0;
    s[t] = v;
    __syncthreads();
    for (int off = 1; off < 256; off <<= 1) {
        int u = (t >= off) ? s[t - off] : 0;
        __syncthreads();
        s[t] += u;
        __syncthreads();
    }
    if (i < NN) rowptr[i] = bsums[blockIdx.x] + s[t] - v;
    if (i == 0) rowptr[NN] = NE;
}

__global__ __launch_bounds__(256) void k_fill(const int* __restrict__ ei, const int* __restrict__ rowptr,
                                              int* __restrict__ cursor, int* __restrict__ colsrc) {
    int e = blockIdx.x * 256 + threadIdx.x;
    if (e < NE) {
        int d = ei[NE + e];
        int pos = rowptr[d] + atomicAdd(&cursor[d], 1);
        colsrc[pos] = ei[e];
    }
}

// ---------------- Aggregation (one wave per node) ----------------
// L=0: gathers fp32 x. L>=1: gathers bf16 h (half the L2/L3 bytes).
// Deferred BN affine applied analytically via prev layer's stats.

__global__ __launch_bounds__(256) void k_agg(
    const float* __restrict__ f32, const ushort_t* __restrict__ fbf,
    const int* __restrict__ rowptr, const int* __restrict__ colsrc,
    const float* __restrict__ stats, const float* __restrict__ bng,
    const float* __restrict__ bnb, float* __restrict__ tout) {
    int n = (blockIdx.x * 256 + threadIdx.x) >> 6;
    int lane = threadIdx.x & 63;
    if (n >= NN) return;
    int beg = rowptr[n], end = rowptr[n + 1];
    float ax = 0.f, ay = 0.f;
    if (fbf != nullptr) {
        const ushort2* h2 = (const ushort2*)fbf;
        int e = beg;
        for (; e + 3 < end; e += 4) {
            int s0 = colsrc[e];
            int s1 = colsrc[e + 1];
            int s2 = colsrc[e + 2];
            int s3 = colsrc[e + 3];
            ushort2 v0 = h2[(size_t)s0 * 64 + lane];
            ushort2 v1 = h2[(size_t)s1 * 64 + lane];
            ushort2 v2 = h2[(size_t)s2 * 64 + lane];
            ushort2 v3 = h2[(size_t)s3 * 64 + lane];
            ax += (bf2f(v0.x) + bf2f(v1.x)) + (bf2f(v2.x) + bf2f(v3.x));
            ay += (bf2f(v0.y) + bf2f(v1.y)) + (bf2f(v2.y) + bf2f(v3.y));
        }
        for (; e < end; ++e) {
            int s0 = colsrc[e];
            ushort2 v0 = h2[(size_t)s0 * 64 + lane];
            ax += bf2f(v0.x);
            ay += bf2f(v0.y);
        }
    } else {
        const float2* f2 = (const float2*)f32;
        int e = beg;
        for (; e + 3 < end; e += 4) {
            int s0 = colsrc[e];
            int s1 = colsrc[e + 1];
            int s2 = colsrc[e + 2];
            int s3 = colsrc[e + 3];
            float2 v0 = f2[(size_t)s0 * 64 + lane];
            float2 v1 = f2[(size_t)s1 * 64 + lane];
            float2 v2 = f2[(size_t)s2 * 64 + lane];
            float2 v3 = f2[(size_t)s3 * 64 + lane];
            ax += (v0.x + v1.x) + (v2.x + v3.x);
            ay += (v0.y + v1.y) + (v2.y + v3.y);
        }
        for (; e < end; ++e) {
            int s0 = colsrc[e];
            float2 v0 = f2[(size_t)s0 * 64 + lane];
            ax += v0.x;
            ay += v0.y;
        }
    }
    float deg = (float)(end - beg);
    float ox, oy;
    if (stats != nullptr) {
        int c0 = lane * 2;
        const float inv_n = 1.0f / (float)NN;
        float m0 = stats[c0] * inv_n, m1 = stats[c0 + 1] * inv_n;
        float var0 = fmaf(-m0, m0, stats[HD + c0] * inv_n);
        float var1 = fmaf(-m1, m1, stats[HD + c0 + 1] * inv_n);
        float sc0 = bng[c0] * rsqrtf(var0 + 1e-5f);
        float sc1 = bng[c0 + 1] * rsqrtf(var1 + 1e-5f);
        float sh0 = bnb[c0] - m0 * sc0;
        float sh1 = bnb[c0 + 1] - m1 * sc1;
        ox = fmaf(sc0, ax, deg * sh0);
        oy = fmaf(sc1, ay, deg * sh1);
    } else {
        ox = ax;
        oy = ay;
    }
    float2 o;
    o.x = ox;
    o.y = oy;
    ((float2*)tout)[(size_t)n * 64 + lane] = o;
}

// ---------------- Conv GEMM: Hbf = bf16(relu(T @ W + b)), per-block BN partials ------
// At fp32 transposed (32 KB, XOR swizzle) + Ws staged in 16 KB quarters -> 48 KB LDS
// -> 3 blocks/CU (3 waves/SIMD). Stats accumulated on the ROUNDED values so BN
// normalization is self-consistent with the bf16 data used downstream.

__global__ __launch_bounds__(256) void k_conv(
    const float* __restrict__ T, const float* __restrict__ W,
    const float* __restrict__ bias, ushort_t* __restrict__ Hbf,
    float* __restrict__ partials) {
    __shared__ float At[128 * 64];   // [k][r^swz]  32 KB
    __shared__ float Ws[32 * 128];   // [kk][c]     16 KB
    int t = threadIdx.x;
    int row0 = blockIdx.x * 64;
    #pragma unroll
    for (int it = 0; it < 8; ++it) {
        int u = t + 256 * it;
        int l = u & 63;
        int gn = u >> 6;
        int r = 8 * (gn & 7) + (l >> 3);
        int k4 = 8 * (gn >> 3) + (l & 7);
        float4 v = make_float4(0.f, 0.f, 0.f, 0.f);
        int row = row0 + r;
        if (row < NN) v = ((const float4*)T)[(size_t)row * 32 + k4];
        int k = 4 * k4;
        int rs = r ^ (8 * (k4 & 7));
        At[(k + 0) * 64 + rs] = v.x;
        At[(k + 1) * 64 + rs] = v.y;
        At[(k + 2) * 64 + rs] = v.z;
        At[(k + 3) * 64 + rs] = v.w;
    }

    int rg = t & 15, cg = t >> 4;
    int r0 = 4 * rg, c0 = 8 * cg;
    float acc[4][8];
    #pragma unroll
    for (int i = 0; i < 4; ++i)
        #pragma unroll
        for (int j = 0; j < 8; ++j) acc[i][j] = 0.f;

    #pragma unroll
    for (int q = 0; q < 4; ++q) {
        if (q) __syncthreads();  // prior quarter's Ws reads done before overwrite
        const float4* Wq = (const float4*)(W + q * 32 * 128);
        #pragma unroll
        for (int it = 0; it < 4; ++it) {
            int id = t + 256 * it;
            ((float4*)Ws)[id] = Wq[id];
        }
        __syncthreads();  // (q==0: also covers At staging)
        #pragma unroll 4
        for (int kk = 0; kk < 32; ++kk) {
            int k = q * 32 + kk;
            float4 a = *(const float4*)&At[k * 64 + (r0 ^ (8 * ((k >> 2) & 7)))];
            const float4* wp = (const float4*)&Ws[kk * 128 + c0];
            float4 w0 = wp[0];
            float4 w1 = wp[1];
            float av[4] = {a.x, a.y, a.z, a.w};
            float wv[8] = {w0.x, w0.y, w0.z, w0.w, w1.x, w1.y, w1.z, w1.w};
            #pragma unroll
            for (int i = 0; i < 4; ++i)
                #pragma unroll
                for (int j = 0; j < 8; ++j) acc[i][j] = fmaf(av[i], wv[j], acc[i][j]);
        }
    }

    float bsv[8];
    #pragma unroll
    for (int j = 0; j < 8; ++j) bsv[j] = bias[c0 + j];
    float lsum[8], lsq[8];
    #pragma unroll
    for (int j = 0; j < 8; ++j) { lsum[j] = 0.f; lsq[j] = 0.f; }
    #pragma unroll
    for (int i = 0; i < 4; ++i) {
        int row = row0 + r0 + i;
        if (row < NN) {
            ushort_t hv[8];
            #pragma unroll
            for (int j = 0; j < 8; ++j) {
                float v = fmaxf(acc[i][j] + bsv[j], 0.f);
                ushort_t b = f2bf(v);
                hv[j] = b;
                float vr = bf2f(b);      // stats on the rounded value
                lsum[j] += vr;
                lsq[j] = fmaf(vr, vr, lsq[j]);
            }
            ushort4* dst = (ushort4*)&Hbf[(size_t)row * 128 + c0];
            dst[0] = make_ushort4(hv[0], hv[1], hv[2], hv[3]);
            dst[1] = make_ushort4(hv[4], hv[5], hv[6], hv[7]);
        }
    }
    #pragma unroll
    for (int off = 1; off < 16; off <<= 1) {
        #pragma unroll
        for (int j = 0; j < 8; ++j) {
            lsum[j] += __shfl_xor(lsum[j], off, 64);
            lsq[j] += __shfl_xor(lsq[j], off, 64);
        }
    }
    if (rg == 0) {
        float* pr = partials + (size_t)blockIdx.x * 256;
        float4* p0 = (float4*)&pr[c0];
        p0[0] = make_float4(lsum[0], lsum[1], lsum[2], lsum[3]);
        p0[1] = make_float4(lsum[4], lsum[5], lsum[6], lsum[7]);
        float4* p1 = (float4*)&pr[HD + c0];
        p1[0] = make_float4(lsq[0], lsq[1], lsq[2], lsq[3]);
        p1[1] = make_float4(lsq[4], lsq[5], lsq[6], lsq[7]);
    }
}

// ---------------- Partial-stats reduction: 1563 x 256 -> 256 ----------------

__global__ __launch_bounds__(256) void k_red(const float* __restrict__ partials,
                                             float* __restrict__ stats) {
    int t = threadIdx.x;
    float s = 0.f;
    for (int r = blockIdx.x; r < NB; r += 16) s += partials[(size_t)r * 256 + t];
    atomicAdd(&stats[t], s);
}

// ---------------- Pooling, phase 1: per-(graph,slice) partial sums (bf16 h) ---------

__device__ __forceinline__ int lowerb(const int* __restrict__ b, int n, int key) {
    int lo = 0, hi = n;
    while (lo < hi) {
        int mid = (lo + hi) >> 1;
        if (b[mid] < key) lo = mid + 1;
        else hi = mid;
    }
    return lo;
}

__global__ __launch_bounds__(256) void k_pool1(
    const ushort_t* __restrict__ h, const int* __restrict__ batch,
    float* __restrict__ ppart) {
    int g = blockIdx.x >> 4;
    int sl = blockIdx.x & (PSL - 1);
    int lo = lowerb(batch, NN, g);
    int hi = lowerb(batch, NN, g + 1);
    int cnt = hi - lo;
    int a = lo + (int)(((long long)cnt * sl) >> 4);
    int b = lo + (int)(((long long)cnt * (sl + 1)) >> 4);
    int wave = threadIdx.x >> 6, lane = threadIdx.x & 63;
    const ushort2* h2 = (const ushort2*)h;
    float ax = 0.f, ay = 0.f;
    for (int n = a + wave; n < b; n += 4) {
        ushort2 v = h2[(size_t)n * 64 + lane];
        ax += bf2f(v.x);
        ay += bf2f(v.y);
    }
    __shared__ float2 red[4][64];
    red[wave][lane] = make_float2(ax, ay);
    __syncthreads();
    if (wave == 0) {
        float sx = 0.f, sy = 0.f;
        for (int w = 0; w < 4; ++w) {
            sx += red[w][lane].x;
            sy += red[w][lane].y;
        }
        ((float2*)ppart)[(size_t)blockIdx.x * 64 + lane] = make_float2(sx, sy);
    }
}

// ---------------- Pooling, phase 2: combine slices + deferred BN affine ----------------

__global__ __launch_bounds__(64) void k_pool2(
    const float* __restrict__ ppart, const int* __restrict__ batch,
    const float* __restrict__ stats, const float* __restrict__ bng, const float* __restrict__ bnb,
    float* __restrict__ pooled) {
    int g = blockIdx.x;
    int lane = threadIdx.x;  // 0..63
    float sx = 0.f, sy = 0.f;
    #pragma unroll
    for (int s = 0; s < PSL; ++s) {
        float2 v = ((const float2*)ppart)[(size_t)(g * PSL + s) * 64 + lane];
        sx += v.x;
        sy += v.y;
    }
    int cnt = lowerb(batch, NN, g + 1) - lowerb(batch, NN, g);
    int c0 = lane * 2;
    const float inv_n = 1.0f / (float)NN;
    float m0 = stats[c0] * inv_n, m1 = stats[c0 + 1] * inv_n;
    float var0 = fmaf(-m0, m0, stats[HD + c0] * inv_n);
    float var1 = fmaf(-m1, m1, stats[HD + c0 + 1] * inv_n);
    float sc0 = bng[c0] * rsqrtf(var0 + 1e-5f);
    float sc1 = bng[c0 + 1] * rsqrtf(var1 + 1e-5f);
    float sh0 = bnb[c0] - m0 * sc0;
    float sh1 = bnb[c0 + 1] - m1 * sc1;
    float denom = fmaxf((float)cnt, 1.f);
    float2 o;
    o.x = (sc0 * sx + (float)cnt * sh0) / denom;
    o.y = (sc1 * sy + (float)cnt * sh1) / denom;
    ((float2*)pooled)[g * 64 + lane] = o;
}

// ---------------- MLP head + log_softmax (one wave per graph) ----------------

__global__ __launch_bounds__(64) void k_head(
    const float* __restrict__ pooled, const float* __restrict__ w1, const float* __restrict__ b1,
    const float* __restrict__ w2, const float* __restrict__ b2, float* __restrict__ out) {
    int g = blockIdx.x;
    int j = threadIdx.x;  // 0..63
    float hid = b1[j];
    const float* p = pooled + g * 128;
    #pragma unroll 8
    for (int k = 0; k < 128; ++k) hid = fmaf(p[k], w1[k * 64 + j], hid);
    float o[4];
    #pragma unroll
    for (int c = 0; c < 4; ++c) {
        float v = hid * w2[j * 4 + c];
        #pragma unroll
        for (int off = 1; off < 64; off <<= 1) v += __shfl_xor(v, off, 64);
        o[c] = v + b2[c];
    }
    if (j == 0) {
        float mx = fmaxf(fmaxf(o[0], o[1]), fmaxf(o[2], o[3]));
        float se = expf(o[0] - mx) + expf(o[1] - mx) + expf(o[2] - mx) + expf(o[3] - mx);
        float ls = mx + logf(se);
        #pragma unroll
        for (int c = 0; c < 4; ++c) out[g * 4 + c] = o[c] - ls;
    }
}

extern "C" void kernel_launch(void* const* d_in, const int* in_sizes, int n_in,
                              void* d_out, int out_size, void* d_ws, size_t ws_size,
                              hipStream_t stream) {
    const float* x = (const float*)d_in[0];
    const int* ei = (const int*)d_in[1];
    const int* batch = (const int*)d_in[2];
    const float* conv_w = (const float*)d_in[3];
    const float* conv_b = (const float*)d_in[4];
    const float* bn_g = (const float*)d_in[5];
    const float* bn_b = (const float*)d_in[6];
    const float* l1w = (const float*)d_in[7];
    const float* l1b = (const float*)d_in[8];
    const float* l2w = (const float*)d_in[9];
    const float* l2b = (const float*)d_in[10];
    float* out = (float*)d_out;
    (void)in_sizes; (void)n_in; (void)out_size; (void)ws_size;

    char* ws = (char*)d_ws;
    int* counts = (int*)(ws + 0);               // 400000 B
    int* cursor = (int*)(ws + 400000);          // 400000 B
    float* stats = (float*)(ws + 800000);       // 6*256 floats = 6144 B
    const size_t zero_bytes = 806144;           // counts + cursor + stats
    int* rowptr = (int*)(ws + 806144);          // 100001 ints
    int* bsums = (int*)(ws + 1206400);          // 391 ints
    int* colsrc = (int*)(ws + 1208192);         // 600000 ints -> ends 3608192
    float* pooled = (float*)(ws + 3608192);     // 64*128 floats -> ends 3640960
    float* ppart = (float*)(ws + 3641344);      // 1024*128 floats = 524288 B -> ends 4165632
    float* partials = (float*)(ws + 4165632);   // 1563*256 floats = 1600512 B -> ends 5766144
    float* tbuf = (float*)(ws + 5767168);       // 51200000 B fp32 T -> ends 56967168
    ushort_t* hbuf = (ushort_t*)(ws + 56967168); // 25600000 B bf16 h -> ends 82567168

    hipMemsetAsync(ws, 0, zero_bytes, stream);

    int ebl = (NE + 255) / 256;
    int nb1 = (NN + 255) / 256;  // 391
    k_hist<<<ebl, 256, 0, stream>>>(ei, counts);
    k_scan1<<<nb1, 256, 0, stream>>>(counts, bsums);
    k_scan2<<<1, 512, 0, stream>>>(bsums, nb1);
    k_scan3<<<nb1, 256, 0, stream>>>(counts, bsums, rowptr);
    k_fill<<<ebl, 256, 0, stream>>>(ei, rowptr, cursor, colsrc);

    const float* fsrc32 = x;
    const ushort_t* fsrcbf = nullptr;
    for (int L = 0; L < NL; ++L) {
        const float* lstats = (L == 0) ? nullptr : (stats + (L - 1) * 256);
        const float* lg = (L == 0) ? nullptr : (bn_g + (L - 1) * 128);
        const float* lb = (L == 0) ? nullptr : (bn_b + (L - 1) * 128);
        k_agg<<<(NN + 3) / 4, 256, 0, stream>>>(fsrc32, fsrcbf, rowptr, colsrc,
                                                lstats, lg, lb, tbuf);
        k_conv<<<NB, 256, 0, stream>>>(tbuf, conv_w + L * 16384, conv_b + L * 128,
                                       hbuf, partials);
        k_red<<<16, 256, 0, stream>>>(partials, stats + L * 256);
        fsrc32 = nullptr;
        fsrcbf = hbuf;
    }
    k_pool1<<<NG * PSL, 256, 0, stream>>>(hbuf, batch, ppart);
    k_pool2<<<NG, 64, 0, stream>>>(ppart, batch, stats + 5 * 256, bn_g + 5 * 128, bn_b + 5 * 128, pooled);
    k_head<<<NG, 64, 0, stream>>>(pooled, l1w, l1b, l2w, l2b, out);
}